// Round 1
// baseline (132.806 us; speedup 1.0000x reference)
//
#include <hip/hip_runtime.h>

#define N_SAMPLES 131072
#define N_FEAT    512
#define N_PAIRS   (N_SAMPLES / 2)
#define N_KER     29
#define MAX_NB    1024

// Kernel 1: per-wave pair processing, per-block partial sums (32 padded
// doubles per block; lanes 29..31 write 0) into d_ws.
__global__ __launch_bounds__(256) void mmd_partial(
    const float* __restrict__ Xs, const float* __restrict__ Xt,
    double* __restrict__ ws, int nwaves) {
  const int tid   = threadIdx.x;
  const int lane  = tid & 63;
  const int wib   = tid >> 6;                  // wave in block, 0..3
  const int gwave = blockIdx.x * 4 + wib;

  // inv_two_gamma_sq[g] = 2^(6 - 0.5*g), exact for this lane's gamma
  const double c = exp2(6.0 - 0.5 * (double)lane);
  double acc = 0.0;                            // lane g < 29: sum of h_u[g, p]

  for (int p = gwave; p < N_PAIRS; p += nwaves) {
    const float* x = Xs + (size_t)2 * (size_t)p * N_FEAT;  // row 2p; row 2p+1 at +512
    const float* y = Xt + (size_t)2 * (size_t)p * N_FEAT;

    double d0 = 0.0, d1 = 0.0, d2 = 0.0, d3 = 0.0;
#pragma unroll
    for (int h = 0; h < 2; ++h) {
      const int off = h * 256 + lane * 4;      // lane-contiguous: wave covers 1024B
      const float4 vx  = *reinterpret_cast<const float4*>(x + off);
      const float4 vxp = *reinterpret_cast<const float4*>(x + N_FEAT + off);
      const float4 vy  = *reinterpret_cast<const float4*>(y + off);
      const float4 vyp = *reinterpret_cast<const float4*>(y + N_FEAT + off);

#define MMD_ACC(A, AP, B, BP)                                   \
      {                                                         \
        const double ax  = (double)(A);                         \
        const double axp = (double)(AP);                        \
        const double ay  = (double)(B);                         \
        const double ayp = (double)(BP);                        \
        double t;                                               \
        t = ax - axp; d0 = fma(t, t, d0);                       \
        t = ay - ayp; d1 = fma(t, t, d1);                       \
        t = ax - ayp; d2 = fma(t, t, d2);                       \
        t = axp - ay; d3 = fma(t, t, d3);                       \
      }
      MMD_ACC(vx.x, vxp.x, vy.x, vyp.x)
      MMD_ACC(vx.y, vxp.y, vy.y, vyp.y)
      MMD_ACC(vx.z, vxp.z, vy.z, vyp.z)
      MMD_ACC(vx.w, vxp.w, vy.w, vyp.w)
#undef MMD_ACC
    }

    // butterfly reduce the 4 distances across all 64 lanes (result in all lanes)
#pragma unroll
    for (int s = 32; s > 0; s >>= 1) {
      d0 += __shfl_xor(d0, s);
      d1 += __shfl_xor(d1, s);
      d2 += __shfl_xor(d2, s);
      d3 += __shfl_xor(d3, s);
    }

    if (lane < N_KER) {
      acc += exp(-d0 * c) + exp(-d1 * c) - exp(-d2 * c) - exp(-d3 * c);
    }
  }

  // block reduction: 4 waves -> 32 padded doubles per block
  __shared__ double sacc[4][32];
  if (lane < 32) sacc[wib][lane] = (lane < N_KER) ? acc : 0.0;
  __syncthreads();
  if (tid < 32) {
    const double s = sacc[0][tid] + sacc[1][tid] + sacc[2][tid] + sacc[3][tid];
    ws[(size_t)blockIdx.x * 32 + tid] = s;
  }
}

// Kernel 2: deterministic reduction over block partials; fold betas; mean.
__global__ __launch_bounds__(256) void mmd_final(
    const double* __restrict__ ws, const float* __restrict__ betas,
    float* __restrict__ out, int nb) {
  const int tid = threadIdx.x;
  double acc = 0.0;
  const int total = nb * 32;
  for (int i = tid; i < total; i += 256) {
    const int g = i & 31;
    if (g < N_KER) acc += (double)betas[g] * ws[i];
  }
  __shared__ double s[256];
  s[tid] = acc;
  __syncthreads();
  for (int ofs = 128; ofs > 0; ofs >>= 1) {
    if (tid < ofs) s[tid] += s[tid + ofs];
    __syncthreads();
  }
  if (tid == 0) out[0] = (float)(s[0] / (double)N_PAIRS);
}

extern "C" void kernel_launch(void* const* d_in, const int* in_sizes, int n_in,
                              void* d_out, int out_size, void* d_ws, size_t ws_size,
                              hipStream_t stream) {
  const float* Xs    = (const float*)d_in[0];
  const float* Xt    = (const float*)d_in[1];
  const float* betas = (const float*)d_in[2];
  float*  out = (float*)d_out;
  double* ws  = (double*)d_ws;

  // Adapt block count to available scratch (32 doubles per block).
  int nb = (int)(ws_size / (32 * sizeof(double)));
  if (nb > MAX_NB) nb = MAX_NB;
  if (nb < 1) nb = 1;

  mmd_partial<<<nb, 256, 0, stream>>>(Xs, Xt, ws, nb * 4);
  mmd_final<<<1, 256, 0, stream>>>(ws, betas, out, nb);
}

// Round 2
// 108.224 us; speedup vs baseline: 1.2271x; 1.2271x over previous
//
#include <hip/hip_runtime.h>

#define N_SAMPLES 131072
#define N_FEAT    512
#define N_PAIRS   (N_SAMPLES / 2)
#define N_KER     29
#define MAX_NB    1024

// 8 float4 = 32 VGPRs of loaded data per pipeline stage.
struct Batch {
  float4 x0, x1, xp0, xp1, y0, y1, yp0, yp1;
};

__device__ __forceinline__ void load_batch(const float* __restrict__ Xs,
                                           const float* __restrict__ Xt,
                                           int p, int o0, Batch& b) {
  const float* x = Xs + (size_t)p * (size_t)(2 * N_FEAT);
  const float* y = Xt + (size_t)p * (size_t)(2 * N_FEAT);
  b.x0  = *reinterpret_cast<const float4*>(x + o0);
  b.x1  = *reinterpret_cast<const float4*>(x + o0 + 256);
  b.xp0 = *reinterpret_cast<const float4*>(x + o0 + N_FEAT);
  b.xp1 = *reinterpret_cast<const float4*>(x + o0 + N_FEAT + 256);
  b.y0  = *reinterpret_cast<const float4*>(y + o0);
  b.y1  = *reinterpret_cast<const float4*>(y + o0 + 256);
  b.yp0 = *reinterpret_cast<const float4*>(y + o0 + N_FEAT);
  b.yp1 = *reinterpret_cast<const float4*>(y + o0 + N_FEAT + 256);
}

__device__ __forceinline__ void compute_pair(const Batch& b, double c, int lane,
                                             double& acc) {
  double d0 = 0.0, d1 = 0.0, d2 = 0.0, d3 = 0.0;

#define MMD_ACC(A, AP, B, BP)                                   \
  {                                                             \
    const double ax  = (double)(A);                             \
    const double axp = (double)(AP);                            \
    const double ay  = (double)(B);                             \
    const double ayp = (double)(BP);                            \
    double t;                                                   \
    t = ax - axp; d0 = fma(t, t, d0);                           \
    t = ay - ayp; d1 = fma(t, t, d1);                           \
    t = ax - ayp; d2 = fma(t, t, d2);                           \
    t = axp - ay; d3 = fma(t, t, d3);                           \
  }
  MMD_ACC(b.x0.x, b.xp0.x, b.y0.x, b.yp0.x)
  MMD_ACC(b.x0.y, b.xp0.y, b.y0.y, b.yp0.y)
  MMD_ACC(b.x0.z, b.xp0.z, b.y0.z, b.yp0.z)
  MMD_ACC(b.x0.w, b.xp0.w, b.y0.w, b.yp0.w)
  MMD_ACC(b.x1.x, b.xp1.x, b.y1.x, b.yp1.x)
  MMD_ACC(b.x1.y, b.xp1.y, b.y1.y, b.yp1.y)
  MMD_ACC(b.x1.z, b.xp1.z, b.y1.z, b.yp1.z)
  MMD_ACC(b.x1.w, b.xp1.w, b.y1.w, b.yp1.w)
#undef MMD_ACC

  // butterfly reduce across 64 lanes (result broadcast to all lanes)
#pragma unroll
  for (int s = 32; s > 0; s >>= 1) {
    d0 += __shfl_xor(d0, s);
    d1 += __shfl_xor(d1, s);
    d2 += __shfl_xor(d2, s);
    d3 += __shfl_xor(d3, s);
  }

  if (lane < N_KER) {
    acc += exp(-d0 * c) + exp(-d1 * c) - exp(-d2 * c) - exp(-d3 * c);
  }
}

// Kernel 1: per-wave pair processing with 2-deep load pipeline; per-block
// partials (32 padded doubles) into d_ws.
__global__ __launch_bounds__(256) void mmd_partial(
    const float* __restrict__ Xs, const float* __restrict__ Xt,
    double* __restrict__ ws, int nwaves) {
  const int tid   = threadIdx.x;
  const int lane  = tid & 63;
  const int wib   = tid >> 6;
  const int gwave = blockIdx.x * 4 + wib;
  const int o0    = lane * 4;

  // inv_two_gamma_sq[g] = 2^(6 - 0.5*g), exact
  const double c = exp2(6.0 - 0.5 * (double)lane);
  double acc = 0.0;

  int p = gwave;
  if (p < N_PAIRS) {
    Batch A, B;
    load_batch(Xs, Xt, p, o0, A);
    int pn = p + nwaves;
    bool pendingA = true;
    while (pn < N_PAIRS) {
      load_batch(Xs, Xt, pn, o0, B);        // issue next loads...
      compute_pair(A, c, lane, acc);        // ...over current compute tail
      pn += nwaves;
      if (pn < N_PAIRS) {
        load_batch(Xs, Xt, pn, o0, A);
        compute_pair(B, c, lane, acc);
        pn += nwaves;
      } else {
        compute_pair(B, c, lane, acc);
        pendingA = false;
        break;
      }
    }
    if (pendingA) compute_pair(A, c, lane, acc);
  }

  // block reduction: 4 waves -> 32 padded doubles
  __shared__ double sacc[4][32];
  if (lane < 32) sacc[wib][lane] = (lane < N_KER) ? acc : 0.0;
  __syncthreads();
  if (tid < 32) {
    const double s = sacc[0][tid] + sacc[1][tid] + sacc[2][tid] + sacc[3][tid];
    ws[(size_t)blockIdx.x * 32 + tid] = s;
  }
}

// Kernel 2: deterministic reduction over block partials; fold betas; mean.
__global__ __launch_bounds__(1024) void mmd_final(
    const double* __restrict__ ws, const float* __restrict__ betas,
    float* __restrict__ out, int nb) {
  const int tid = threadIdx.x;
  double acc = 0.0;
  const int total = nb * 32;
  for (int i = tid; i < total; i += 1024) {
    const int g = i & 31;
    if (g < N_KER) acc += (double)betas[g] * ws[i];
  }
  __shared__ double s[1024];
  s[tid] = acc;
  __syncthreads();
  for (int ofs = 512; ofs > 0; ofs >>= 1) {
    if (tid < ofs) s[tid] += s[tid + ofs];
    __syncthreads();
  }
  if (tid == 0) out[0] = (float)(s[0] / (double)N_PAIRS);
}

extern "C" void kernel_launch(void* const* d_in, const int* in_sizes, int n_in,
                              void* d_out, int out_size, void* d_ws, size_t ws_size,
                              hipStream_t stream) {
  const float* Xs    = (const float*)d_in[0];
  const float* Xt    = (const float*)d_in[1];
  const float* betas = (const float*)d_in[2];
  float*  out = (float*)d_out;
  double* ws  = (double*)d_ws;

  int nb = (int)(ws_size / (32 * sizeof(double)));
  if (nb > MAX_NB) nb = MAX_NB;
  if (nb < 1) nb = 1;

  mmd_partial<<<nb, 256, 0, stream>>>(Xs, Xt, ws, nb * 4);
  mmd_final<<<1, 1024, 0, stream>>>(ws, betas, out, nb);
}